// Round 9
// baseline (215.970 us; speedup 1.0000x reference)
//
#include <hip/hip_runtime.h>
#include <hip/hip_bf16.h>

typedef __attribute__((ext_vector_type(8))) short short8;
typedef __attribute__((ext_vector_type(4))) float floatx4;

#define MFMA16(a, b, c) __builtin_amdgcn_mfma_f32_16x16x32_bf16((a), (b), (c), 0, 0, 0)
#define WAIT_VM(N) asm volatile("s_waitcnt vmcnt(" #N ")" ::: "memory")
#define BAR() __builtin_amdgcn_s_barrier()

__device__ __forceinline__ short f2bf(float f) {
    union { float f; unsigned u; } x; x.f = f;
    unsigned r = (x.u + 0x7fffu + ((x.u >> 16) & 1u)) >> 16;
    return (short)r;
}
__device__ __forceinline__ float b2f(short s) {
    union { unsigned u; float f; } x; x.u = ((unsigned)(unsigned short)s) << 16; return x.f;
}
__device__ __forceinline__ int swap5(int p) { return ((p & 31) << 5) | (p >> 5); }  // involution

// async global->LDS, 16B per lane; LDS dest is wave-uniform base + lane*16
__device__ __forceinline__ void gl2lds16(const short* g, short* l) {
    void* gv = const_cast<short*>(g);
    __builtin_amdgcn_global_load_lds((__attribute__((address_space(1))) void*)gv,
                                     (__attribute__((address_space(3))) void*)l,
                                     16, 0, 0);
}

// ======== merged prep: weight casts/transpose + all bias dot-products, one launch ========
__global__ __launch_bounds__(256) void prep_all(const float* __restrict__ Wq,
                                                const float* __restrict__ Wk,
                                                const float* __restrict__ Wv,
                                                const float* __restrict__ Wn,
                                                const float* __restrict__ bq,
                                                const float* __restrict__ bk,
                                                const float* __restrict__ bv,
                                                short* __restrict__ Wqc, short* __restrict__ Wkc,
                                                short* __restrict__ Wvc, short* __restrict__ Wnt,
                                                float* __restrict__ UVC) {
    __shared__ float t[32][33];
    __shared__ float red2[4][64];
    const int bid = blockIdx.x, tid = threadIdx.x;
    if (bid < 1024) {
        int z = bid >> 8, rem = bid & 255;
        int o0 = (rem & 15) * 32, c0 = (rem >> 4) * 32;
        int lx = tid & 31, ly = tid >> 5;
        if (z < 3) {
            const float* src = (z == 0) ? Wq : (z == 1) ? Wk : Wv;
            short* dst = (z == 0) ? Wqc : (z == 1) ? Wkc : Wvc;
            for (int i = ly; i < 32; i += 8) {
                size_t idx = (size_t)(c0 + i) * 512 + o0 + lx;
                dst[idx] = f2bf(src[idx]);
            }
        } else {
            for (int i = ly; i < 32; i += 8) t[i][lx] = Wn[(size_t)(c0 + i) * 512 + o0 + lx];
            __syncthreads();
            for (int i = ly; i < 32; i += 8)
                Wnt[(size_t)(o0 + i) * 512 + c0 + lx] = f2bf(t[lx][i]);
        }
    } else if (bid < 1152) {
        const int wv = tid >> 6, ln = tid & 63;
        const int r = (bid - 1024) * 4 + wv;
        const float4* wq4 = (const float4*)(Wq + (size_t)r * 512);
        const float4* wk4 = (const float4*)(Wk + (size_t)r * 512);
        const float4* bk4 = (const float4*)bk;
        const float4* bq4 = (const float4*)bq;
        float su = 0.f, sv = 0.f;
#pragma unroll
        for (int j = 0; j < 2; ++j) {
            int i = ln * 2 + j;
            float4 a = wq4[i], b = bk4[i];
            su += a.x * b.x + a.y * b.y + a.z * b.z + a.w * b.w;
            float4 c = wk4[i], d = bq4[i];
            sv += c.x * d.x + c.y * d.y + c.z * d.z + c.w * d.w;
        }
#pragma unroll
        for (int off = 32; off > 0; off >>= 1) {
            su += __shfl_xor(su, off, 64);
            sv += __shfl_xor(sv, off, 64);
        }
        if (ln == 0) { UVC[r] = su; UVC[512 + r] = sv; }
    } else if (bid == 1152) {
        if (tid < 64) {
            const float4* a4 = (const float4*)bq;
            const float4* b4 = (const float4*)bk;
            float s = 0.f;
#pragma unroll
            for (int j = 0; j < 2; ++j) {
                int i = tid * 2 + j;
                float4 a = a4[i], b = b4[i];
                s += a.x * b.x + a.y * b.y + a.z * b.z + a.w * b.w;
            }
#pragma unroll
            for (int off = 32; off > 0; off >>= 1) s += __shfl_xor(s, off, 64);
            if (tid == 0) UVC[1024] = s;
        }
    } else {
        const int j = bid - 1153;            // [0,8)
        const int w = tid >> 6, lt = tid & 63;
        const int tcol = j * 64 + lt;
        float s = 0.f;
        for (int o = w * 128; o < w * 128 + 128; ++o) s += bv[o] * Wn[(size_t)o * 512 + tcol];
        red2[w][lt] = s;
        __syncthreads();
        if (tid < 64)
            UVC[1025 + j * 64 + tid] = red2[0][tid] + red2[1][tid] + red2[2][tid] + red2[3][tid];
    }
}

// ======== 512^3 weight GEMMs, K-split x4 into fp32 partials ========
__global__ __launch_bounds__(256) void gemm2p(const short* __restrict__ Wkc,
                                              const short* __restrict__ Wqc,
                                              const short* __restrict__ Wnt,
                                              const short* __restrict__ Wvc,
                                              float* __restrict__ Pacc) {
    const int tid = threadIdx.x;
    const int wv = tid >> 6, ln = tid & 63;
    const int z = blockIdx.z, ksl = blockIdx.y;
    const int kbase = ksl * 128;
    const short* A  = (z == 0) ? Wkc : Wnt;
    const short* Wt = (z == 0) ? Wqc : Wvc;
    float* P = Pacc + (size_t)(z * 4 + ksl) * 262144;
    const int m0 = (blockIdx.x & 3) * 128, n0 = (blockIdx.x >> 2) * 128;

    __shared__ __attribute__((aligned(16))) short As[3][128 * 32];
    __shared__ __attribute__((aligned(16))) short Bs[3][128 * 32];

    floatx4 acc[4][4] = {};
    const int wm = (wv >> 1) * 64, wn = (wv & 1) * 64;
    const int fr = ln & 15, fq = ln >> 4;

    int sr[2], sq[2];
#pragma unroll
    for (int j = 0; j < 2; ++j) {
        int s = (wv * 2 + j) * 64 + ln;
        sr[j] = s >> 2;
        sq[j] = ((s & 3) ^ ((sr[j] >> 1) & 3)) * 8;
    }
    int aoff[4], boff[4];
#pragma unroll
    for (int t = 0; t < 4; ++t) {
        int ra = wm + t * 16 + fr;
        aoff[t] = ra * 32 + ((fq ^ ((ra >> 1) & 3)) * 8);
        int rb = wn + t * 16 + fr;
        boff[t] = rb * 32 + ((fq ^ ((rb >> 1) & 3)) * 8);
    }

    short* a0 = &As[0][0]; short* a1 = &As[1][0]; short* a2 = &As[2][0];
    short* b0 = &Bs[0][0]; short* b1 = &Bs[1][0]; short* b2 = &Bs[2][0];

#pragma unroll
    for (int j = 0; j < 2; ++j) {
        gl2lds16(A  + (size_t)(m0 + sr[j]) * 512 + kbase + sq[j],      a0 + (wv * 2 + j) * 512);
        gl2lds16(Wt + (size_t)(n0 + sr[j]) * 512 + kbase + sq[j],      b0 + (wv * 2 + j) * 512);
        gl2lds16(A  + (size_t)(m0 + sr[j]) * 512 + kbase + 32 + sq[j], a1 + (wv * 2 + j) * 512);
        gl2lds16(Wt + (size_t)(n0 + sr[j]) * 512 + kbase + 32 + sq[j], b1 + (wv * 2 + j) * 512);
    }

    auto compute = [&](const short* Ap, const short* Bp) {
        short8 af[4], bfr[4];
#pragma unroll
        for (int t = 0; t < 4; ++t) {
            af[t]  = *(const short8*)(Ap + aoff[t]);
            bfr[t] = *(const short8*)(Bp + boff[t]);
        }
#pragma unroll
        for (int mt = 0; mt < 4; ++mt)
#pragma unroll
            for (int nt = 0; nt < 4; ++nt)
                acc[mt][nt] = MFMA16(af[mt], bfr[nt], acc[mt][nt]);
    };

    for (int t = 0; t < 2; ++t) {
        int kp = kbase + t * 32 + 64;
#pragma unroll
        for (int j = 0; j < 2; ++j) {
            gl2lds16(A  + (size_t)(m0 + sr[j]) * 512 + kp + sq[j], a2 + (wv * 2 + j) * 512);
            gl2lds16(Wt + (size_t)(n0 + sr[j]) * 512 + kp + sq[j], b2 + (wv * 2 + j) * 512);
        }
        WAIT_VM(8);
        BAR();
        compute(a0, b0);
        BAR();
        short* ta = a0; a0 = a1; a1 = a2; a2 = ta;
        short* tb = b0; b0 = b1; b1 = b2; b2 = tb;
    }
    WAIT_VM(4); BAR();
    compute(a0, b0);
    WAIT_VM(0); BAR();
    compute(a1, b1);

#pragma unroll
    for (int mt = 0; mt < 4; ++mt)
#pragma unroll
        for (int nt = 0; nt < 4; ++nt) {
            int n = n0 + wn + nt * 16 + fr;
#pragma unroll
            for (int r = 0; r < 4; ++r) {
                int m = m0 + wm + mt * 16 + fq * 4 + r;
                P[(size_t)m * 512 + n] = acc[mt][nt][r];
            }
        }
}

// -------- reduce 4 K-partials + cast to bf16: Gt (z=0), W2t (z=1) --------
__global__ __launch_bounds__(256) void reduce_cast(const float* __restrict__ Pacc,
                                                   short* __restrict__ Gt,
                                                   short* __restrict__ W2t) {
    const int bid = blockIdx.x, tid = threadIdx.x;
    const int z = bid >> 8;
    const int off = (bid & 255) * 1024 + tid * 4;
    const float* base = Pacc + (size_t)z * 4 * 262144 + off;
    float4 s0 = *(const float4*)(base);
    float4 s1 = *(const float4*)(base + 262144);
    float4 s2 = *(const float4*)(base + 2 * 262144);
    float4 s3 = *(const float4*)(base + 3 * 262144);
    short* dst = z ? W2t : Gt;
    short4 o;
    o.x = f2bf(s0.x + s1.x + s2.x + s3.x);
    o.y = f2bf(s0.y + s1.y + s2.y + s3.y);
    o.z = f2bf(s0.z + s1.z + s2.z + s3.z);
    o.w = f2bf(s0.w + s1.w + s2.w + s3.w);
    *(short4*)(dst + off) = o;
}

// ---------------- groupnorm: x[b][c][p] -> hnt[b][p][c] bf16 ----------------
__global__ __launch_bounds__(256) void groupnorm_k(const float* __restrict__ x,
                                                   short* __restrict__ hnt) {
    int b = blockIdx.x >> 5, g = blockIdx.x & 31;
    const float* xg = x + ((size_t)b * 512 + g * 16) * 1024;   // 16 rows x 1024
    const float4* xg4 = (const float4*)xg;
    float s = 0.f, ss = 0.f;
    for (int i = threadIdx.x; i < 4096; i += 256) {
        float4 v = xg4[i];
        s  += v.x + v.y + v.z + v.w;
        ss += v.x * v.x + v.y * v.y + v.z * v.z + v.w * v.w;
    }
#pragma unroll
    for (int off = 32; off > 0; off >>= 1) {
        s  += __shfl_down(s,  off, 64);
        ss += __shfl_down(ss, off, 64);
    }
    __shared__ float red[8];
    int w = threadIdx.x >> 6;
    if ((threadIdx.x & 63) == 0) { red[w] = s; red[4 + w] = ss; }
    __syncthreads();
    float S  = red[0] + red[1] + red[2] + red[3];
    float SS = red[4] + red[5] + red[6] + red[7];
    float mean = S * (1.f / 16384.f);
    float var  = SS * (1.f / 16384.f) - mean * mean;
    float rstd = rsqrtf(var + 1e-5f);
    __shared__ __attribute__((aligned(16))) short tile[16 * 1026];
    for (int i = threadIdx.x; i < 4096; i += 256) {
        float4 v = xg4[i];
        int c = i >> 8, p = (i & 255) * 4;
        short* tp = tile + c * 1026 + p;
        tp[0] = f2bf((v.x - mean) * rstd);
        tp[1] = f2bf((v.y - mean) * rstd);
        tp[2] = f2bf((v.z - mean) * rstd);
        tp[3] = f2bf((v.w - mean) * rstd);
    }
    __syncthreads();
    for (int i = threadIdx.x; i < 2048; i += 256) {
        int p = i >> 1, half = i & 1;
        short8 v;
#pragma unroll
        for (int j = 0; j < 8; ++j) v[j] = tile[(half * 8 + j) * 1026 + p];
        *(short8*)(hnt + ((size_t)b * 1024 + p) * 512 + g * 16 + half * 8) = v;
    }
}

// ------------- per-row bias dots: RuP[swap5(p)]=h_p.u, RvP[swap5(p)]=h_p.v -------------
__global__ __launch_bounds__(256) void ruv_k(const short* __restrict__ hnt,
                                             const float* __restrict__ UVC,
                                             float* __restrict__ RuP,
                                             float* __restrict__ RvP) {
    const int b = blockIdx.x >> 4, part = blockIdx.x & 15;
    const int wv = threadIdx.x >> 6, ln = threadIdx.x & 63;
    float uc[8], vc[8];
#pragma unroll
    for (int j = 0; j < 8; ++j) { uc[j] = UVC[ln * 8 + j]; vc[j] = UVC[512 + ln * 8 + j]; }
    for (int rr = 0; rr < 16; ++rr) {
        int p = part * 64 + wv * 16 + rr;
        short8 h = *(const short8*)(hnt + ((size_t)b * 1024 + p) * 512 + ln * 8);
        float su = 0.f, sv = 0.f;
#pragma unroll
        for (int j = 0; j < 8; ++j) { float hv = b2f(h[j]); su += hv * uc[j]; sv += hv * vc[j]; }
#pragma unroll
        for (int off = 32; off > 0; off >>= 1) {
            su += __shfl_xor(su, off, 64);
            sv += __shfl_xor(sv, off, 64);
        }
        if (ln == 0) {
            int pp = swap5(p);
            RuP[(size_t)b * 1024 + pp] = su;
            RvP[(size_t)b * 1024 + pp] = sv;
        }
    }
}

// ------- T-GEMM, 128x256 tiles: Tp[b][swap5(m)][c'] = hnt[b][m][:].Gt[c'][:] -------
__global__ __launch_bounds__(256, 2) void tgemm(const short* __restrict__ A,
                                                const short* __restrict__ Gt,
                                                short* __restrict__ Tp) {
    const int tid = threadIdx.x;
    const int wv = tid >> 6, ln = tid & 63;
    const int fid = blockIdx.x;                     // [0,256)
    const int xcd = fid & 7, slot = fid >> 3;       // slot [0,32)
    const int bb = (slot >= 16) ? 1 : 0;
    const int w = slot - bb * 16;                   // [0,16)
    const int batch = xcd * 2 + bb;
    const int m0 = (w & 7) * 128, n0 = (w >> 3) * 256;
    const size_t BS = 1024 * 512;
    const short* Ab = A + (size_t)batch * BS;
    short* Ob = Tp + (size_t)batch * BS;

    __shared__ __attribute__((aligned(16))) short As[3][128 * 32];
    __shared__ __attribute__((aligned(16))) short Bs[3][256 * 32];

    floatx4 acc[4][8] = {};
    const int wm = (wv >> 1) * 64, wn = (wv & 1) * 128;
    const int fr = ln & 15, fq = ln >> 4;

    const short* pA[2];
    const short* pB[4];
#pragma unroll
    for (int j = 0; j < 2; ++j) {
        int s = (wv * 2 + j) * 64 + ln;
        int r = s >> 2;
        int q = ((s & 3) ^ ((r >> 1) & 3)) * 8;
        pA[j] = Ab + (size_t)(m0 + r) * 512 + q;
    }
#pragma unroll
    for (int j = 0; j < 4; ++j) {
        int s = (wv * 4 + j) * 64 + ln;
        int r = s >> 2;
        int q = ((s & 3) ^ ((r >> 1) & 3)) * 8;
        pB[j] = Gt + (size_t)(n0 + r) * 512 + q;
    }
    int aoff[4], boff[8];
#pragma unroll
    for (int t = 0; t < 4; ++t) {
        int ra = wm + t * 16 + fr;
        aoff[t] = ra * 32 + ((fq ^ ((ra >> 1) & 3)) * 8);
    }
#pragma unroll
    for (int u = 0; u < 8; ++u) {
        int rb = wn + u * 16 + fr;
        boff[u] = rb * 32 + ((fq ^ ((rb >> 1) & 3)) * 8);
    }

    short* a0 = &As[0][0]; short* a1 = &As[1][0]; short* a2 = &As[2][0];
    short* b0 = &Bs[0][0]; short* b1 = &Bs[1][0]; short* b2 = &Bs[2][0];

#pragma unroll
    for (int j = 0; j < 2; ++j) {
        gl2lds16(pA[j],      a0 + (wv * 2 + j) * 512);
        gl2lds16(pA[j] + 32, a1 + (wv * 2 + j) * 512);
    }
#pragma unroll
    for (int j = 0; j < 4; ++j) {
        gl2lds16(pB[j],      b0 + (wv * 4 + j) * 512);
        gl2lds16(pB[j] + 32, b1 + (wv * 4 + j) * 512);
    }

    auto compute = [&](const short* Ap, const short* Bp) {
        short8 af[4], bfr[8];
#pragma unroll
        for (int t = 0; t < 4; ++t) af[t] = *(const short8*)(Ap + aoff[t]);
#pragma unroll
        for (int u = 0; u < 8; ++u) bfr[u] = *(const short8*)(Bp + boff[u]);
#pragma unroll
        for (int mt = 0; mt < 4; ++mt)
#pragma unroll
            for (int nt = 0; nt < 8; ++nt)
                acc[mt][nt] = MFMA16(af[mt], bfr[nt], acc[mt][nt]);
    };

    for (int t = 0; t < 14; ++t) {
        int kp = t * 32 + 64;
#pragma unroll
        for (int j = 0; j < 2; ++j)
            gl2lds16(pA[j] + kp, a2 + (wv * 2 + j) * 512);
#pragma unroll
        for (int j = 0; j < 4; ++j)
            gl2lds16(pB[j] + kp, b2 + (wv * 4 + j) * 512);
        WAIT_VM(12);
        BAR();
        compute(a0, b0);
        BAR();
        short* ta = a0; a0 = a1; a1 = a2; a2 = ta;
        short* tb = b0; b0 = b1; b1 = b2; b2 = tb;
    }
    WAIT_VM(6); BAR();
    compute(a0, b0);
    WAIT_VM(0); BAR();
    compute(a1, b1);

#pragma unroll
    for (int mt = 0; mt < 4; ++mt)
#pragma unroll
        for (int nt = 0; nt < 8; ++nt) {
            int n = n0 + wn + nt * 16 + fr;
#pragma unroll
            for (int r = 0; r < 4; ++r) {
                int m = m0 + wm + mt * 16 + fq * 4 + r;
                Ob[(size_t)swap5(m) * 512 + n] = f2bf(acc[mt][nt][r]);
            }
        }
}

// ---------------- fused S-GEMM + softmax diagonal: A=Tp, B=hnt(swap5 rows) ----------------
__global__ __launch_bounds__(256, 2) void attn_sm(const short* __restrict__ Tp,
                                                  const short* __restrict__ H,
                                                  const float* __restrict__ RuP,
                                                  const float* __restrict__ RvP,
                                                  const float* __restrict__ UVC,
                                                  float* __restrict__ Dm) {
    const int tid = threadIdx.x;
    const int wv = tid >> 6, ln = tid & 63;
    const int fid = blockIdx.x + (blockIdx.y << 3) + blockIdx.z * 32;
    const int xcd = fid & 7, slot = fid >> 3;
    const int bb = (slot >= 32) ? 1 : 0;
    const int w = slot - bb * 32;
    const int b = xcd * 2 + bb;
    const int m0 = (w & 7) * 128, n0 = (w >> 3) * 256;
    const size_t BS = 1024 * 512;
    const short* Tb = Tp + (size_t)b * BS;
    const short* Hb = H + (size_t)b * BS;

    __shared__ __attribute__((aligned(16))) short As[3][128 * 32];
    __shared__ __attribute__((aligned(16))) short Bs[3][256 * 32];

    floatx4 acc[4][8] = {};
    const int wm = (wv >> 1) * 64, wn = (wv & 1) * 128;
    const int fr = ln & 15, fq = ln >> 4;

    const short* pA[2];
    const short* pB[4];
#pragma unroll
    for (int j = 0; j < 2; ++j) {
        int s = (wv * 2 + j) * 64 + ln;
        int r = s >> 2;
        int q = ((s & 3) ^ ((r >> 1) & 3)) * 8;
        pA[j] = Tb + (size_t)(m0 + r) * 512 + q;
    }
#pragma unroll
    for (int j = 0; j < 4; ++j) {
        int s = (wv * 4 + j) * 64 + ln;
        int r = s >> 2;
        int q = ((s & 3) ^ ((r >> 1) & 3)) * 8;
        pB[j] = Hb + (size_t)swap5(n0 + r) * 512 + q;   // permuted source row
    }
    int aoff[4], boff[8];
#pragma unroll
    for (int t = 0; t < 4; ++t) {
        int ra = wm + t * 16 + fr;
        aoff[t] = ra * 32 + ((fq ^ ((ra >> 1) & 3)) * 8);
    }
#pragma unroll
    for (int u = 0; u < 8; ++u) {
        int rb = wn + u * 16 + fr;
        boff[u] = rb * 32 + ((fq ^ ((rb >> 1) & 3)) * 8);
    }

    short* a0 = &As[0][0]; short* a1 = &As[1][0]; short* a2 = &As[2][0];
    short* b0 = &Bs[0][0]; short* b1 = &Bs[1][0]; short* b2 = &Bs[2][0];

#pragma unroll
    for (int j = 0; j < 2; ++j) {
        gl2lds16(pA[j],      a0 + (wv * 2 + j) * 512);
        gl2lds16(pA[j] + 32, a1 + (wv * 2 + j) * 512);
    }
#pragma unroll
    for (int j = 0; j < 4; ++j) {
        gl2lds16(pB[j],      b0 + (wv * 4 + j) * 512);
        gl2lds16(pB[j] + 32, b1 + (wv * 4 + j) * 512);
    }

    auto compute = [&](const short* Ap, const short* Bp) {
        short8 af[4], bfr[8];
#pragma unroll
        for (int t = 0; t < 4; ++t) af[t] = *(const short8*)(Ap + aoff[t]);
#pragma unroll
        for (int u = 0; u < 8; ++u) bfr[u] = *(const short8*)(Bp + boff[u]);
#pragma unroll
        for (int mt = 0; mt < 4; ++mt)
#pragma unroll
            for (int nt = 0; nt < 8; ++nt)
                acc[mt][nt] = MFMA16(af[mt], bfr[nt], acc[mt][nt]);
    };

    for (int t = 0; t < 14; ++t) {
        int kp = t * 32 + 64;
#pragma unroll
        for (int j = 0; j < 2; ++j)
            gl2lds16(pA[j] + kp, a2 + (wv * 2 + j) * 512);
#pragma unroll
        for (int j = 0; j < 4; ++j)
            gl2lds16(pB[j] + kp, b2 + (wv * 4 + j) * 512);
        WAIT_VM(12);
        BAR();
        compute(a0, b0);
        BAR();
        short* ta = a0; a0 = a1; a1 = a2; a2 = ta;
        short* tb = b0; b0 = b1; b1 = b2; b2 = tb;
    }
    WAIT_VM(6); BAR();
    compute(a0, b0);
    WAIT_VM(0); BAR();
    compute(a1, b1);

    // ---- per-slice softmax-diagonal with bias terms (zero-valued on bench inputs) ----
    const float scale = 0.04419417382415922f;  // 512^-0.5
    const float c0v = UVC[1024];
    const int wbase = (m0 + wm) >> 5;
    const int Wbase = (n0 + wn) >> 5;
#pragma unroll
    for (int si = 0; si < 2; ++si) {
#pragma unroll
        for (int sj = 0; sj < 4; ++sj) {
            int wg = wbase + si, Wg = Wbase + sj;
            float tv[16];
            float mx = -3.0e38f;
#pragma unroll
            for (int mi = 0; mi < 2; ++mi) {
                float4 ru4 = *(const float4*)(RuP + (size_t)b * 1024 + m0 + wm + (2 * si + mi) * 16 + fq * 4);
                const float* rup = (const float*)&ru4;
#pragma unroll
                for (int ni = 0; ni < 2; ++ni) {
                    float rvv = RvP[(size_t)b * 1024 + n0 + wn + (2 * sj + ni) * 16 + fr];
#pragma unroll
                    for (int r = 0; r < 4; ++r) {
                        float u = (acc[2 * si + mi][2 * sj + ni][r] + rup[r] + rvv + c0v) * scale;
                        tv[(mi * 2 + ni) * 4 + r] = u;
                        mx = fmaxf(mx, u);
                    }
                }
            }
#pragma unroll
            for (int off = 32; off > 0; off >>= 1) mx = fmaxf(mx, __shfl_xor(mx, off, 64));
            float se = 0.f;
#pragma unroll
            for (int i = 0; i < 16; ++i) se += __expf(tv[i] - mx);
#pragma unroll
            for (int off = 32; off > 0; off >>= 1) se += __shfl_xor(se, off, 64);
            if (fq == ((wg >> 2) & 3) && fr == (Wg & 15)) {
                int mi = wg >> 4, ni = Wg >> 4;
                float numer = tv[(mi * 2 + ni) * 4 + (wg & 3)];
                Dm[((size_t)b * 32 + wg) * 32 + Wg] = __expf(numer - mx) / se;
            }
        }
    }
}

// -- out-GEMM, 128x256 tiles: out[b][n][m] = x + D[b][m]*(hnt[m].W2t[n] + w2b[n]) + bn[n] --
__global__ __launch_bounds__(256, 2) void out_gemm(const short* __restrict__ A,
                                                   const short* __restrict__ Wt,
                                                   const float* __restrict__ UVC,
                                                   const float* __restrict__ Dm,
                                                   const float* __restrict__ bnb,
                                                   const float* __restrict__ x,
                                                   float* __restrict__ out) {
    const int tid = threadIdx.x;
    const int wv = tid >> 6, ln = tid & 63;
    const int fid = blockIdx.x;                     // [0,256)
    const int xcd = fid & 7, slot = fid >> 3;       // [0,32)
    const int bb = (slot >= 16) ? 1 : 0;
    const int w = slot - bb * 16;                   // [0,16)
    const int b = xcd * 2 + bb;
    const int m0 = (w & 7) * 128, n0 = (w >> 3) * 256;
    const size_t BS = 1024 * 512;
    const short* Ab = A + (size_t)b * BS;

    __shared__ __attribute__((aligned(16))) short As[3][128 * 32];
    __shared__ __attribute__((aligned(16))) short Bs[3][256 * 32];

    floatx4 acc[4][8] = {};
    const int wm = (wv >> 1) * 64, wn = (wv & 1) * 128;
    const int fr = ln & 15, fq = ln >> 4;

    const short* pA[2];
    const short* pB[4];
#pragma unroll
    for (int j = 0; j < 2; ++j) {
        int s = (wv * 2 + j) * 64 + ln;
        int r = s >> 2;
        int q = ((s & 3) ^ ((r >> 1) & 3)) * 8;
        pA[j] = Ab + (size_t)(m0 + r) * 512 + q;
    }
#pragma unroll
    for (int j = 0; j < 4; ++j) {
        int s = (wv * 4 + j) * 64 + ln;
        int r = s >> 2;
        int q = ((s & 3) ^ ((r >> 1) & 3)) * 8;
        pB[j] = Wt + (size_t)(n0 + r) * 512 + q;
    }
    int aoff[4], boff[8];
#pragma unroll
    for (int t = 0; t < 4; ++t) {
        int ra = wm + t * 16 + fr;
        aoff[t] = ra * 32 + ((fq ^ ((ra >> 1) & 3)) * 8);
    }
#pragma unroll
    for (int u = 0; u < 8; ++u) {
        int rb = wn + u * 16 + fr;
        boff[u] = rb * 32 + ((fq ^ ((rb >> 1) & 3)) * 8);
    }

    short* a0 = &As[0][0]; short* a1 = &As[1][0]; short* a2 = &As[2][0];
    short* b0 = &Bs[0][0]; short* b1 = &Bs[1][0]; short* b2 = &Bs[2][0];

#pragma unroll
    for (int j = 0; j < 2; ++j) {
        gl2lds16(pA[j],      a0 + (wv * 2 + j) * 512);
        gl2lds16(pA[j] + 32, a1 + (wv * 2 + j) * 512);
    }
#pragma unroll
    for (int j = 0; j < 4; ++j) {
        gl2lds16(pB[j],      b0 + (wv * 4 + j) * 512);
        gl2lds16(pB[j] + 32, b1 + (wv * 4 + j) * 512);
    }

    auto compute = [&](const short* Ap, const short* Bp) {
        short8 af[4], bfr[8];
#pragma unroll
        for (int t = 0; t < 4; ++t) af[t] = *(const short8*)(Ap + aoff[t]);
#pragma unroll
        for (int u = 0; u < 8; ++u) bfr[u] = *(const short8*)(Bp + boff[u]);
#pragma unroll
        for (int mt = 0; mt < 4; ++mt)
#pragma unroll
            for (int nt = 0; nt < 8; ++nt)
                acc[mt][nt] = MFMA16(af[mt], bfr[nt], acc[mt][nt]);
    };

    for (int t = 0; t < 14; ++t) {
        int kp = t * 32 + 64;
#pragma unroll
        for (int j = 0; j < 2; ++j)
            gl2lds16(pA[j] + kp, a2 + (wv * 2 + j) * 512);
#pragma unroll
        for (int j = 0; j < 4; ++j)
            gl2lds16(pB[j] + kp, b2 + (wv * 4 + j) * 512);
        WAIT_VM(12);
        BAR();
        compute(a0, b0);
        BAR();
        short* ta = a0; a0 = a1; a1 = a2; a2 = ta;
        short* tb = b0; b0 = b1; b1 = b2; b2 = tb;
    }
    WAIT_VM(6); BAR();
    compute(a0, b0);
    WAIT_VM(0); BAR();
    compute(a1, b1);

#pragma unroll
    for (int mt = 0; mt < 4; ++mt) {
        int mbase = m0 + wm + mt * 16 + fq * 4;
        float4 d4 = *(const float4*)(Dm + (size_t)b * 1024 + mbase);
#pragma unroll
        for (int nt = 0; nt < 8; ++nt) {
            int n = n0 + wn + nt * 16 + fr;
            float bvv = bnb[n];
            float w2bn = UVC[1025 + n];
            size_t base = ((size_t)b * 512 + n) * 1024 + mbase;
            float4 x4 = *(const float4*)(x + base);
            float4 o;
            o.x = x4.x + d4.x * (acc[mt][nt][0] + w2bn) + bvv;
            o.y = x4.y + d4.y * (acc[mt][nt][1] + w2bn) + bvv;
            o.z = x4.z + d4.z * (acc[mt][nt][2] + w2bn) + bvv;
            o.w = x4.w + d4.w * (acc[mt][nt][3] + w2bn) + bvv;
            *(float4*)(out + base) = o;
        }
    }
}

extern "C" void kernel_launch(void* const* d_in, const int* in_sizes, int n_in,
                              void* d_out, int out_size, void* d_ws, size_t ws_size,
                              hipStream_t stream) {
    const float* x  = (const float*)d_in[0];
    const float* Wq = (const float*)d_in[1];
    const float* bq = (const float*)d_in[2];
    const float* Wk = (const float*)d_in[3];
    const float* bk = (const float*)d_in[4];
    const float* Wv = (const float*)d_in[5];
    const float* bv = (const float*)d_in[6];
    const float* Wn = (const float*)d_in[7];
    const float* bn = (const float*)d_in[8];
    float* out = (float*)d_out;
    char* ws = (char*)d_ws;

    const size_t WSZ = (size_t)512 * 512 * 2;         // 0.52 MB per weight
    const size_t TSZ = (size_t)16 * 1024 * 512 * 2;   // 16.78 MB
    short* Wqc = (short*)(ws);
    short* Wkc = (short*)(ws + WSZ);
    short* Wvc = (short*)(ws + 2 * WSZ);
    short* Wnt = (short*)(ws + 3 * WSZ);
    short* Gt  = (short*)(ws + 4 * WSZ);
    short* W2t = (short*)(ws + 5 * WSZ);
    float* UVC = (float*)(ws + 6 * WSZ);              // 1537 floats
    float* RuP = (float*)(ws + 6 * WSZ + 8192);
    float* RvP = (float*)(ws + 6 * WSZ + 8192 + 65536);
    float* Dm  = (float*)(ws + 6 * WSZ + 8192 + 2 * 65536);
    float* Pacc = (float*)(ws + 6 * WSZ + 8192 + 3 * 65536);   // 8 MB fp32 partials
    char*  big = ws + 6 * WSZ + 8192 + 3 * 65536 + 8388608;
    short* hnt = (short*)(big);
    short* Tp  = (short*)(big + TSZ);

    prep_all<<<1161, 256, 0, stream>>>(Wq, Wk, Wv, Wn, bq, bk, bv, Wqc, Wkc, Wvc, Wnt, UVC);
    gemm2p<<<dim3(16, 4, 2), 256, 0, stream>>>(Wkc, Wqc, Wnt, Wvc, Pacc);
    reduce_cast<<<512, 256, 0, stream>>>(Pacc, Gt, W2t);
    groupnorm_k<<<512, 256, 0, stream>>>(x, hnt);
    ruv_k<<<256, 256, 0, stream>>>(hnt, UVC, RuP, RvP);
    tgemm<<<256, 256, 0, stream>>>(hnt, Gt, Tp);
    attn_sm<<<dim3(8, 4, 16), 256, 0, stream>>>(Tp, hnt, RuP, RvP, UVC, Dm);
    out_gemm<<<256, 256, 0, stream>>>(hnt, W2t, UVC, Dm, bn, x, out);
}

// Round 10
// 205.557 us; speedup vs baseline: 1.0507x; 1.0507x over previous
//
#include <hip/hip_runtime.h>
#include <hip/hip_bf16.h>

typedef __attribute__((ext_vector_type(8))) short short8;
typedef __attribute__((ext_vector_type(4))) float floatx4;

#define MFMA16(a, b, c) __builtin_amdgcn_mfma_f32_16x16x32_bf16((a), (b), (c), 0, 0, 0)
#define WAIT_VM(N) asm volatile("s_waitcnt vmcnt(" #N ")" ::: "memory")
#define BAR() __builtin_amdgcn_s_barrier()

__device__ __forceinline__ short f2bf(float f) {
    union { float f; unsigned u; } x; x.f = f;
    unsigned r = (x.u + 0x7fffu + ((x.u >> 16) & 1u)) >> 16;
    return (short)r;
}

// async global->LDS, 16B per lane; LDS dest is wave-uniform base + lane*16
__device__ __forceinline__ void gl2lds16(const short* g, short* l) {
    void* gv = const_cast<short*>(g);
    __builtin_amdgcn_global_load_lds((__attribute__((address_space(1))) void*)gv,
                                     (__attribute__((address_space(3))) void*)l,
                                     16, 0, 0);
}

// ------------- weight prep: 4 transposes (fp32->bf16) + bias concat, one launch -------------
__global__ void transpose_w4(const float* __restrict__ Wq, const float* __restrict__ Wk,
                             const float* __restrict__ Wv, const float* __restrict__ Wn,
                             const float* __restrict__ bq, const float* __restrict__ bk,
                             const float* __restrict__ bv,
                             short* __restrict__ Wqkv_t, short* __restrict__ Wn_t,
                             float* __restrict__ bias_cat) {
    __shared__ float t[32][33];
    int z = blockIdx.z;
    const float* Wsrc = (z == 0) ? Wq : (z == 1) ? Wk : (z == 2) ? Wv : Wn;
    int o0 = blockIdx.x * 32, c0 = blockIdx.y * 32;
    int lx = threadIdx.x, ly = threadIdx.y;   // (32,8)
    for (int i = ly; i < 32; i += 8) t[i][lx] = Wsrc[(size_t)(c0 + i) * 512 + o0 + lx];
    __syncthreads();
    for (int i = ly; i < 32; i += 8) {
        short v = f2bf(t[lx][i]);
        if (z < 3) Wqkv_t[(size_t)(z * 512 + o0 + i) * 512 + c0 + lx] = v;
        else       Wn_t[(size_t)(o0 + i) * 512 + c0 + lx] = v;
    }
    if (z < 3 && blockIdx.y == 0 && ly == 0) {
        const float* bsrc = (z == 0) ? bq : (z == 1) ? bk : bv;
        bias_cat[z * 512 + o0 + lx] = bsrc[o0 + lx];
    }
}

// ---------------- groupnorm: x[b][c][p] -> hnt[b][p][c] bf16 ----------------
__global__ __launch_bounds__(256) void groupnorm_k(const float* __restrict__ x,
                                                   short* __restrict__ hnt) {
    int b = blockIdx.x >> 5, g = blockIdx.x & 31;
    const float* xg = x + ((size_t)b * 512 + g * 16) * 1024;   // 16 rows x 1024
    const float4* xg4 = (const float4*)xg;
    float s = 0.f, ss = 0.f;
    for (int i = threadIdx.x; i < 4096; i += 256) {
        float4 v = xg4[i];
        s  += v.x + v.y + v.z + v.w;
        ss += v.x * v.x + v.y * v.y + v.z * v.z + v.w * v.w;
    }
#pragma unroll
    for (int off = 32; off > 0; off >>= 1) {
        s  += __shfl_down(s,  off, 64);
        ss += __shfl_down(ss, off, 64);
    }
    __shared__ float red[8];
    int w = threadIdx.x >> 6;
    if ((threadIdx.x & 63) == 0) { red[w] = s; red[4 + w] = ss; }
    __syncthreads();
    float S  = red[0] + red[1] + red[2] + red[3];
    float SS = red[4] + red[5] + red[6] + red[7];
    float mean = S * (1.f / 16384.f);
    float var  = SS * (1.f / 16384.f) - mean * mean;
    float rstd = rsqrtf(var + 1e-5f);
    __shared__ __attribute__((aligned(16))) short tile[16 * 1026];
    for (int i = threadIdx.x; i < 4096; i += 256) {
        float4 v = xg4[i];
        int c = i >> 8, p = (i & 255) * 4;
        short* tp = tile + c * 1026 + p;
        tp[0] = f2bf((v.x - mean) * rstd);
        tp[1] = f2bf((v.y - mean) * rstd);
        tp[2] = f2bf((v.z - mean) * rstd);
        tp[3] = f2bf((v.w - mean) * rstd);
    }
    __syncthreads();
    for (int i = threadIdx.x; i < 2048; i += 256) {
        int p = i >> 1, half = i & 1;
        short8 v;
#pragma unroll
        for (int j = 0; j < 8; ++j) v[j] = tile[(half * 8 + j) * 1026 + p];
        *(short8*)(hnt + ((size_t)b * 1024 + p) * 512 + g * 16 + half * 8) = v;
    }
}

// ---------------- fused QKV GEMM: N=1536 over concat weights ----------------
// plain blockIdx mapping (r2-measured: 41.3us vs 45.1 with XCD remap), hoisted offsets,
// 3-stage LDS pipeline with counted vmcnt.
__global__ __launch_bounds__(256) void qkv_gemm(const short* __restrict__ A,
                                                const short* __restrict__ Wt,
                                                const float* __restrict__ bias_cat,
                                                short* __restrict__ Qp,
                                                short* __restrict__ Kp,
                                                short* __restrict__ Vb) {
    const int tid = threadIdx.x;
    const int wv = tid >> 6, ln = tid & 63;
    const int m0 = blockIdx.x * 128, n0 = blockIdx.y * 128;
    const int batch = blockIdx.z;
    const size_t BS = 1024 * 512;
    const short* Ab = A + (size_t)batch * BS;
    const int tsel = n0 >> 9;
    const int permute = (tsel < 2);
    short* Ob = ((tsel == 0) ? Qp : (tsel == 1) ? Kp : Vb) + (size_t)batch * BS;

    __shared__ __attribute__((aligned(16))) short As[3][128 * 32];
    __shared__ __attribute__((aligned(16))) short Bs[3][128 * 32];

    floatx4 acc[4][4] = {};
    const int wm = (wv >> 1) * 64, wn = (wv & 1) * 64;
    const int fr = ln & 15, fq = ln >> 4;

    int sr[2], sq[2];
#pragma unroll
    for (int j = 0; j < 2; ++j) {
        int s = (wv * 2 + j) * 64 + ln;
        sr[j] = s >> 2;
        sq[j] = ((s & 3) ^ ((sr[j] >> 1) & 3)) * 8;
    }
    // loop-invariant LDS fragment read offsets
    int aoff[4], boff[4];
#pragma unroll
    for (int t = 0; t < 4; ++t) {
        int ra = wm + t * 16 + fr;
        aoff[t] = ra * 32 + ((fq ^ ((ra >> 1) & 3)) * 8);
        int rb = wn + t * 16 + fr;
        boff[t] = rb * 32 + ((fq ^ ((rb >> 1) & 3)) * 8);
    }

    short* a0 = &As[0][0]; short* a1 = &As[1][0]; short* a2 = &As[2][0];
    short* b0 = &Bs[0][0]; short* b1 = &Bs[1][0]; short* b2 = &Bs[2][0];

    // stage tiles 0 and 1 (4 loads each per wave)
#pragma unroll
    for (int j = 0; j < 2; ++j) {
        gl2lds16(Ab + (size_t)(m0 + sr[j]) * 512 + sq[j],      a0 + (wv * 2 + j) * 512);
        gl2lds16(Wt + (size_t)(n0 + sr[j]) * 512 + sq[j],      b0 + (wv * 2 + j) * 512);
        gl2lds16(Ab + (size_t)(m0 + sr[j]) * 512 + 32 + sq[j], a1 + (wv * 2 + j) * 512);
        gl2lds16(Wt + (size_t)(n0 + sr[j]) * 512 + 32 + sq[j], b1 + (wv * 2 + j) * 512);
    }

    auto compute = [&](const short* Ap, const short* Bp) {
        short8 af[4], bfr[4];
#pragma unroll
        for (int t = 0; t < 4; ++t) {
            af[t]  = *(const short8*)(Ap + aoff[t]);
            bfr[t] = *(const short8*)(Bp + boff[t]);
        }
#pragma unroll
        for (int mt = 0; mt < 4; ++mt)
#pragma unroll
            for (int nt = 0; nt < 4; ++nt)
                acc[mt][nt] = MFMA16(af[mt], bfr[nt], acc[mt][nt]);
    };

    for (int t = 0; t < 14; ++t) {
        int kp = t * 32 + 64;   // prefetch tile t+2
#pragma unroll
        for (int j = 0; j < 2; ++j) {
            gl2lds16(Ab + (size_t)(m0 + sr[j]) * 512 + kp + sq[j], a2 + (wv * 2 + j) * 512);
            gl2lds16(Wt + (size_t)(n0 + sr[j]) * 512 + kp + sq[j], b2 + (wv * 2 + j) * 512);
        }
        WAIT_VM(8);            // tile t's 4 loads (oldest) done; t+1,t+2 in flight
        BAR();
        compute(a0, b0);
        BAR();                 // all waves done reading tile t's buffer; safe to DMA into it
        short* ta = a0; a0 = a1; a1 = a2; a2 = ta;
        short* tb = b0; b0 = b1; b1 = b2; b2 = tb;
    }
    WAIT_VM(4); BAR();
    compute(a0, b0);           // tile 14
    WAIT_VM(0); BAR();
    compute(a1, b1);           // tile 15

#pragma unroll
    for (int mt = 0; mt < 4; ++mt) {
#pragma unroll
        for (int nt = 0; nt < 4; ++nt) {
            int n = n0 + wn + nt * 16 + fr;
            float bvv = bias_cat[n];
            int nn = n & 511;
#pragma unroll
            for (int r = 0; r < 4; ++r) {
                int m = m0 + wm + mt * 16 + fq * 4 + r;
                int mrow = permute ? ((m & 31) * 32 + (m >> 5)) : m;
                Ob[(size_t)mrow * 512 + nn] = f2bf(acc[mt][nt][r] + bvv);
            }
        }
    }
}

// ---------------- fused S-GEMM + per-32x32-block softmax diagonal, 128x256 tiles ----------------
__global__ __launch_bounds__(256, 2) void attn_sm(const short* __restrict__ Qp,
                                                  const short* __restrict__ Kp,
                                                  float* __restrict__ Dm) {
    const int tid = threadIdx.x;
    const int wv = tid >> 6, ln = tid & 63;
    // flat id in [0,512); each xcd gets 64 slots = 2 batches x 32 tiles
    const int fid = blockIdx.x + (blockIdx.y << 3) + blockIdx.z * 32;
    const int xcd = fid & 7, slot = fid >> 3;
    const int bb = (slot >= 32) ? 1 : 0;
    const int w = slot - bb * 32;            // [0,32)
    const int b = xcd * 2 + bb;
    const int m0 = (w & 7) * 128, n0 = (w >> 3) * 256;
    const short* Qb = Qp + (size_t)b * (1024 * 512);
    const short* Kb = Kp + (size_t)b * (1024 * 512);

    __shared__ __attribute__((aligned(16))) short As[3][128 * 32];
    __shared__ __attribute__((aligned(16))) short Bs[3][256 * 32];

    floatx4 acc[4][8] = {};
    const int wm = (wv >> 1) * 64, wn = (wv & 1) * 128;
    const int fr = ln & 15, fq = ln >> 4;

    int ar[2], aq[2], br[4], bq_[4];
#pragma unroll
    for (int j = 0; j < 2; ++j) {
        int s = (wv * 2 + j) * 64 + ln;
        ar[j] = s >> 2;
        aq[j] = ((s & 3) ^ ((ar[j] >> 1) & 3)) * 8;
    }
#pragma unroll
    for (int j = 0; j < 4; ++j) {
        int s = (wv * 4 + j) * 64 + ln;
        br[j] = s >> 2;
        bq_[j] = ((s & 3) ^ ((br[j] >> 1) & 3)) * 8;
    }
    int aoff[4], boff[8];
#pragma unroll
    for (int t = 0; t < 4; ++t) {
        int ra = wm + t * 16 + fr;
        aoff[t] = ra * 32 + ((fq ^ ((ra >> 1) & 3)) * 8);
    }
#pragma unroll
    for (int u = 0; u < 8; ++u) {
        int rb = wn + u * 16 + fr;
        boff[u] = rb * 32 + ((fq ^ ((rb >> 1) & 3)) * 8);
    }

    short* a0 = &As[0][0]; short* a1 = &As[1][0]; short* a2 = &As[2][0];
    short* b0 = &Bs[0][0]; short* b1 = &Bs[1][0]; short* b2 = &Bs[2][0];

    // stage tiles 0 and 1 (6 loads each per wave)
#pragma unroll
    for (int j = 0; j < 2; ++j) {
        gl2lds16(Qb + (size_t)(m0 + ar[j]) * 512 + aq[j],      a0 + (wv * 2 + j) * 512);
        gl2lds16(Qb + (size_t)(m0 + ar[j]) * 512 + 32 + aq[j], a1 + (wv * 2 + j) * 512);
    }
#pragma unroll
    for (int j = 0; j < 4; ++j) {
        gl2lds16(Kb + (size_t)(n0 + br[j]) * 512 + bq_[j],      b0 + (wv * 4 + j) * 512);
        gl2lds16(Kb + (size_t)(n0 + br[j]) * 512 + 32 + bq_[j], b1 + (wv * 4 + j) * 512);
    }

    auto compute = [&](const short* Ap, const short* Bp) {
        short8 af[4], bfr[8];
#pragma unroll
        for (int t = 0; t < 4; ++t) af[t] = *(const short8*)(Ap + aoff[t]);
#pragma unroll
        for (int u = 0; u < 8; ++u) bfr[u] = *(const short8*)(Bp + boff[u]);
#pragma unroll
        for (int mt = 0; mt < 4; ++mt)
#pragma unroll
            for (int nt = 0; nt < 8; ++nt)
                acc[mt][nt] = MFMA16(af[mt], bfr[nt], acc[mt][nt]);
    };

    for (int t = 0; t < 14; ++t) {
        int kp = t * 32 + 64;   // prefetch tile t+2
#pragma unroll
        for (int j = 0; j < 2; ++j)
            gl2lds16(Qb + (size_t)(m0 + ar[j]) * 512 + kp + aq[j], a2 + (wv * 2 + j) * 512);
#pragma unroll
        for (int j = 0; j < 4; ++j)
            gl2lds16(Kb + (size_t)(n0 + br[j]) * 512 + kp + bq_[j], b2 + (wv * 4 + j) * 512);
        WAIT_VM(12);           // tile t's 6 loads done; 12 newer in flight
        BAR();
        compute(a0, b0);
        BAR();
        short* ta = a0; a0 = a1; a1 = a2; a2 = ta;
        short* tb = b0; b0 = b1; b1 = b2; b2 = tb;
    }
    WAIT_VM(6); BAR();
    compute(a0, b0);           // tile 14
    WAIT_VM(0); BAR();
    compute(a1, b1);           // tile 15

    // ---- per-slice softmax-diagonal (2x4 = 8 slices per wave) ----
    const float scale = 0.04419417382415922f;  // 512^-0.5
    const int wbase = (m0 + wm) >> 5;
    const int Wbase = (n0 + wn) >> 5;
#pragma unroll
    for (int si = 0; si < 2; ++si) {
#pragma unroll
        for (int sj = 0; sj < 4; ++sj) {
            int wg = wbase + si, Wg = Wbase + sj;
            float tv[16];
            float mx = -3.0e38f;
#pragma unroll
            for (int mi = 0; mi < 2; ++mi)
#pragma unroll
                for (int ni = 0; ni < 2; ++ni)
#pragma unroll
                    for (int r = 0; r < 4; ++r) {
                        float u = acc[2 * si + mi][2 * sj + ni][r] * scale;
                        tv[(mi * 2 + ni) * 4 + r] = u;
                        mx = fmaxf(mx, u);
                    }
#pragma unroll
            for (int off = 32; off > 0; off >>= 1) mx = fmaxf(mx, __shfl_xor(mx, off, 64));
            float se = 0.f;
#pragma unroll
            for (int i = 0; i < 16; ++i) se += __expf(tv[i] - mx);
#pragma unroll
            for (int off = 32; off > 0; off >>= 1) se += __shfl_xor(se, off, 64);
            if (fq == ((wg >> 2) & 3) && fr == (Wg & 15)) {
                int mi = wg >> 4, ni = Wg >> 4;
                float numer = tv[(mi * 2 + ni) * 4 + (wg & 3)];
                Dm[((size_t)b * 32 + wg) * 32 + Wg] = __expf(numer - mx) / se;
            }
        }
    }
}

// ---------------- fused out-GEMM: out[b][n][m] = x + D[b][m]*(V.Wn)[m][n] + bn[n] ----------------
__global__ __launch_bounds__(256) void out_gemm(const short* __restrict__ A,
                                                const short* __restrict__ Wt,
                                                const float* __restrict__ Dm,
                                                const float* __restrict__ bnb,
                                                const float* __restrict__ x,
                                                float* __restrict__ out) {
    const int tid = threadIdx.x;
    const int wv = tid >> 6, ln = tid & 63;
    const int fid = blockIdx.x + (blockIdx.y << 3) + blockIdx.z * 32;
    const int xcd = fid & 7, slot = fid >> 3;
    const int bb = (slot >= 32) ? 1 : 0;
    const int w = slot - bb * 32;
    const int b = xcd * 2 + bb;
    const int m0 = (w & 7) * 128, n0 = (w >> 3) * 128;
    const size_t BS = 1024 * 512;
    const short* Ab = A + (size_t)b * BS;

    __shared__ __attribute__((aligned(16))) short As[3][128 * 32];
    __shared__ __attribute__((aligned(16))) short Bs[3][128 * 32];

    floatx4 acc[4][4] = {};
    const int wm = (wv >> 1) * 64, wn = (wv & 1) * 64;
    const int fr = ln & 15, fq = ln >> 4;

    int sr[2], sq[2];
#pragma unroll
    for (int j = 0; j < 2; ++j) {
        int s = (wv * 2 + j) * 64 + ln;
        sr[j] = s >> 2;
        sq[j] = ((s & 3) ^ ((sr[j] >> 1) & 3)) * 8;
    }
    int aoff[4], boff[4];
#pragma unroll
    for (int t = 0; t < 4; ++t) {
        int ra = wm + t * 16 + fr;
        aoff[t] = ra * 32 + ((fq ^ ((ra >> 1) & 3)) * 8);
        int rb = wn + t * 16 + fr;
        boff[t] = rb * 32 + ((fq ^ ((rb >> 1) & 3)) * 8);
    }

    short* a0 = &As[0][0]; short* a1 = &As[1][0]; short* a2 = &As[2][0];
    short* b0 = &Bs[0][0]; short* b1 = &Bs[1][0]; short* b2 = &Bs[2][0];

#pragma unroll
    for (int j = 0; j < 2; ++j) {
        gl2lds16(Ab + (size_t)(m0 + sr[j]) * 512 + sq[j],      a0 + (wv * 2 + j) * 512);
        gl2lds16(Wt + (size_t)(n0 + sr[j]) * 512 + sq[j],      b0 + (wv * 2 + j) * 512);
        gl2lds16(Ab + (size_t)(m0 + sr[j]) * 512 + 32 + sq[j], a1 + (wv * 2 + j) * 512);
        gl2lds16(Wt + (size_t)(n0 + sr[j]) * 512 + 32 + sq[j], b1 + (wv * 2 + j) * 512);
    }

    auto compute = [&](const short* Ap, const short* Bp) {
        short8 af[4], bfr[4];
#pragma unroll
        for (int t = 0; t < 4; ++t) {
            af[t]  = *(const short8*)(Ap + aoff[t]);
            bfr[t] = *(const short8*)(Bp + boff[t]);
        }
#pragma unroll
        for (int mt = 0; mt < 4; ++mt)
#pragma unroll
            for (int nt = 0; nt < 4; ++nt)
                acc[mt][nt] = MFMA16(af[mt], bfr[nt], acc[mt][nt]);
    };

    for (int t = 0; t < 14; ++t) {
        int kp = t * 32 + 64;
#pragma unroll
        for (int j = 0; j < 2; ++j) {
            gl2lds16(Ab + (size_t)(m0 + sr[j]) * 512 + kp + sq[j], a2 + (wv * 2 + j) * 512);
            gl2lds16(Wt + (size_t)(n0 + sr[j]) * 512 + kp + sq[j], b2 + (wv * 2 + j) * 512);
        }
        WAIT_VM(8);
        BAR();
        compute(a0, b0);
        BAR();
        short* ta = a0; a0 = a1; a1 = a2; a2 = ta;
        short* tb = b0; b0 = b1; b1 = b2; b2 = tb;
    }
    WAIT_VM(4); BAR();
    compute(a0, b0);
    WAIT_VM(0); BAR();
    compute(a1, b1);

#pragma unroll
    for (int mt = 0; mt < 4; ++mt) {
        int mbase = m0 + wm + mt * 16 + fq * 4;
        float4 d4 = *(const float4*)(Dm + (size_t)b * 1024 + mbase);
#pragma unroll
        for (int nt = 0; nt < 4; ++nt) {
            int n = n0 + wn + nt * 16 + fr;
            float bvv = bnb[n];
            size_t base = ((size_t)b * 512 + n) * 1024 + mbase;
            float4 x4 = *(const float4*)(x + base);
            float4 o;
            o.x = x4.x + d4.x * acc[mt][nt][0] + bvv;
            o.y = x4.y + d4.y * acc[mt][nt][1] + bvv;
            o.z = x4.z + d4.z * acc[mt][nt][2] + bvv;
            o.w = x4.w + d4.w * acc[mt][nt][3] + bvv;
            *(float4*)(out + base) = o;
        }
    }
}

extern "C" void kernel_launch(void* const* d_in, const int* in_sizes, int n_in,
                              void* d_out, int out_size, void* d_ws, size_t ws_size,
                              hipStream_t stream) {
    const float* x  = (const float*)d_in[0];
    const float* Wq = (const float*)d_in[1];
    const float* bq = (const float*)d_in[2];
    const float* Wk = (const float*)d_in[3];
    const float* bk = (const float*)d_in[4];
    const float* Wv = (const float*)d_in[5];
    const float* bv = (const float*)d_in[6];
    const float* Wn = (const float*)d_in[7];
    const float* bn = (const float*)d_in[8];
    float* out = (float*)d_out;
    char* ws = (char*)d_ws;

    const size_t WQKV = (size_t)1536 * 512 * 2;       // 1.57 MB
    const size_t WSZ  = (size_t)512 * 512 * 2;        // 0.52 MB
    const size_t BIAS = 1536 * sizeof(float);
    const size_t TSZ  = (size_t)16 * 1024 * 512 * 2;  // 16.78 MB
    short* Wqkv_t   = (short*)(ws);
    short* Wn_t     = (short*)(ws + WQKV);
    float* bias_cat = (float*)(ws + WQKV + WSZ);
    char*  base     = ws + WQKV + WSZ + BIAS;
    short* hnt = (short*)(base);
    short* Qp  = (short*)(base + TSZ);
    short* Kp  = (short*)(base + 2 * TSZ);
    short* Vb  = (short*)(base + 3 * TSZ);
    float* Dm  = (float*)(base + 4 * TSZ);            // 16*1024 fp32

    transpose_w4<<<dim3(16, 16, 4), dim3(32, 8), 0, stream>>>(
        Wq, Wk, Wv, Wn, bq, bk, bv, Wqkv_t, Wn_t, bias_cat);
    groupnorm_k<<<512, 256, 0, stream>>>(x, hnt);
    qkv_gemm<<<dim3(8, 12, 16), 256, 0, stream>>>(hnt, Wqkv_t, bias_cat, Qp, Kp, Vb);
    attn_sm<<<dim3(8, 4, 16), 256, 0, stream>>>(Qp, Kp, Dm);
    out_gemm<<<dim3(8, 4, 16), 256, 0, stream>>>(Vb, Wn_t, Dm, bn, x, out);
}

// Round 11
// 199.925 us; speedup vs baseline: 1.0803x; 1.0282x over previous
//
#include <hip/hip_runtime.h>
#include <hip/hip_bf16.h>

typedef __attribute__((ext_vector_type(8))) short short8;
typedef __attribute__((ext_vector_type(4))) float floatx4;

#define MFMA16(a, b, c) __builtin_amdgcn_mfma_f32_16x16x32_bf16((a), (b), (c), 0, 0, 0)
#define WAIT_VM(N) asm volatile("s_waitcnt vmcnt(" #N ")" ::: "memory")
#define BAR() __builtin_amdgcn_s_barrier()

__device__ __forceinline__ short f2bf(float f) {
    union { float f; unsigned u; } x; x.f = f;
    unsigned r = (x.u + 0x7fffu + ((x.u >> 16) & 1u)) >> 16;
    return (short)r;
}

// async global->LDS, 16B per lane; LDS dest is wave-uniform base + lane*16
__device__ __forceinline__ void gl2lds16(const short* g, short* l) {
    void* gv = const_cast<short*>(g);
    __builtin_amdgcn_global_load_lds((__attribute__((address_space(1))) void*)gv,
                                     (__attribute__((address_space(3))) void*)l,
                                     16, 0, 0);
}

// ------------- weight prep: 4 transposes (fp32->bf16) + bias concat, one launch -------------
__global__ void transpose_w4(const float* __restrict__ Wq, const float* __restrict__ Wk,
                             const float* __restrict__ Wv, const float* __restrict__ Wn,
                             const float* __restrict__ bq, const float* __restrict__ bk,
                             const float* __restrict__ bv,
                             short* __restrict__ Wqkv_t, short* __restrict__ Wn_t,
                             float* __restrict__ bias_cat) {
    __shared__ float t[32][33];
    int z = blockIdx.z;
    const float* Wsrc = (z == 0) ? Wq : (z == 1) ? Wk : (z == 2) ? Wv : Wn;
    int o0 = blockIdx.x * 32, c0 = blockIdx.y * 32;
    int lx = threadIdx.x, ly = threadIdx.y;   // (32,8)
    for (int i = ly; i < 32; i += 8) t[i][lx] = Wsrc[(size_t)(c0 + i) * 512 + o0 + lx];
    __syncthreads();
    for (int i = ly; i < 32; i += 8) {
        short v = f2bf(t[lx][i]);
        if (z < 3) Wqkv_t[(size_t)(z * 512 + o0 + i) * 512 + c0 + lx] = v;
        else       Wn_t[(size_t)(o0 + i) * 512 + c0 + lx] = v;
    }
    if (z < 3 && blockIdx.y == 0 && ly == 0) {
        const float* bsrc = (z == 0) ? bq : (z == 1) ? bk : bv;
        bias_cat[z * 512 + o0 + lx] = bsrc[o0 + lx];
    }
}

// ---------------- groupnorm: x[b][c][p] -> hnt[b][p][c] bf16 ----------------
__global__ __launch_bounds__(256) void groupnorm_k(const float* __restrict__ x,
                                                   short* __restrict__ hnt) {
    int b = blockIdx.x >> 5, g = blockIdx.x & 31;
    const float* xg = x + ((size_t)b * 512 + g * 16) * 1024;   // 16 rows x 1024
    const float4* xg4 = (const float4*)xg;
    float s = 0.f, ss = 0.f;
    for (int i = threadIdx.x; i < 4096; i += 256) {
        float4 v = xg4[i];
        s  += v.x + v.y + v.z + v.w;
        ss += v.x * v.x + v.y * v.y + v.z * v.z + v.w * v.w;
    }
#pragma unroll
    for (int off = 32; off > 0; off >>= 1) {
        s  += __shfl_down(s,  off, 64);
        ss += __shfl_down(ss, off, 64);
    }
    __shared__ float red[8];
    int w = threadIdx.x >> 6;
    if ((threadIdx.x & 63) == 0) { red[w] = s; red[4 + w] = ss; }
    __syncthreads();
    float S  = red[0] + red[1] + red[2] + red[3];
    float SS = red[4] + red[5] + red[6] + red[7];
    float mean = S * (1.f / 16384.f);
    float var  = SS * (1.f / 16384.f) - mean * mean;
    float rstd = rsqrtf(var + 1e-5f);
    __shared__ __attribute__((aligned(16))) short tile[16 * 1026];
    for (int i = threadIdx.x; i < 4096; i += 256) {
        float4 v = xg4[i];
        int c = i >> 8, p = (i & 255) * 4;
        short* tp = tile + c * 1026 + p;
        tp[0] = f2bf((v.x - mean) * rstd);
        tp[1] = f2bf((v.y - mean) * rstd);
        tp[2] = f2bf((v.z - mean) * rstd);
        tp[3] = f2bf((v.w - mean) * rstd);
    }
    __syncthreads();
    for (int i = threadIdx.x; i < 2048; i += 256) {
        int p = i >> 1, half = i & 1;
        short8 v;
#pragma unroll
        for (int j = 0; j < 8; ++j) v[j] = tile[(half * 8 + j) * 1026 + p];
        *(short8*)(hnt + ((size_t)b * 1024 + p) * 512 + g * 16 + half * 8) = v;
    }
}

// ---------------- fused QKV GEMM: N=1536 over concat weights, 128x256 tiles ----------------
// attn_sm-style wide-B structure: 32 MFMA per barrier phase (vs 16 at 128x128),
// amortizing the per-phase WAIT+BAR stall over 2x compute. N-tiles of 256 never
// straddle the 512-boundaries between Q/K/V. Plain blockIdx mapping (r10-verified).
__global__ __launch_bounds__(256, 2) void qkv_gemm(const short* __restrict__ A,
                                                   const short* __restrict__ Wt,
                                                   const float* __restrict__ bias_cat,
                                                   short* __restrict__ Qp,
                                                   short* __restrict__ Kp,
                                                   short* __restrict__ Vb) {
    const int tid = threadIdx.x;
    const int wv = tid >> 6, ln = tid & 63;
    const int m0 = blockIdx.x * 128, n0 = blockIdx.y * 256;
    const int batch = blockIdx.z;
    const size_t BS = 1024 * 512;
    const short* Ab = A + (size_t)batch * BS;
    const int tsel = n0 >> 9;
    const int permute = (tsel < 2);
    short* Ob = ((tsel == 0) ? Qp : (tsel == 1) ? Kp : Vb) + (size_t)batch * BS;

    __shared__ __attribute__((aligned(16))) short As[3][128 * 32];
    __shared__ __attribute__((aligned(16))) short Bs[3][256 * 32];

    floatx4 acc[4][8] = {};
    const int wm = (wv >> 1) * 64, wn = (wv & 1) * 128;
    const int fr = ln & 15, fq = ln >> 4;

    int ar[2], aq[2], br[4], bq_[4];
#pragma unroll
    for (int j = 0; j < 2; ++j) {
        int s = (wv * 2 + j) * 64 + ln;
        ar[j] = s >> 2;
        aq[j] = ((s & 3) ^ ((ar[j] >> 1) & 3)) * 8;
    }
#pragma unroll
    for (int j = 0; j < 4; ++j) {
        int s = (wv * 4 + j) * 64 + ln;
        br[j] = s >> 2;
        bq_[j] = ((s & 3) ^ ((br[j] >> 1) & 3)) * 8;
    }
    int aoff[4], boff[8];
#pragma unroll
    for (int t = 0; t < 4; ++t) {
        int ra = wm + t * 16 + fr;
        aoff[t] = ra * 32 + ((fq ^ ((ra >> 1) & 3)) * 8);
    }
#pragma unroll
    for (int u = 0; u < 8; ++u) {
        int rb = wn + u * 16 + fr;
        boff[u] = rb * 32 + ((fq ^ ((rb >> 1) & 3)) * 8);
    }

    short* a0 = &As[0][0]; short* a1 = &As[1][0]; short* a2 = &As[2][0];
    short* b0 = &Bs[0][0]; short* b1 = &Bs[1][0]; short* b2 = &Bs[2][0];

    // stage tiles 0 and 1 (6 loads each per wave)
#pragma unroll
    for (int j = 0; j < 2; ++j) {
        gl2lds16(Ab + (size_t)(m0 + ar[j]) * 512 + aq[j],      a0 + (wv * 2 + j) * 512);
        gl2lds16(Ab + (size_t)(m0 + ar[j]) * 512 + 32 + aq[j], a1 + (wv * 2 + j) * 512);
    }
#pragma unroll
    for (int j = 0; j < 4; ++j) {
        gl2lds16(Wt + (size_t)(n0 + br[j]) * 512 + bq_[j],      b0 + (wv * 4 + j) * 512);
        gl2lds16(Wt + (size_t)(n0 + br[j]) * 512 + 32 + bq_[j], b1 + (wv * 4 + j) * 512);
    }

    auto compute = [&](const short* Ap, const short* Bp) {
        short8 af[4], bfr[8];
#pragma unroll
        for (int t = 0; t < 4; ++t) af[t] = *(const short8*)(Ap + aoff[t]);
#pragma unroll
        for (int u = 0; u < 8; ++u) bfr[u] = *(const short8*)(Bp + boff[u]);
#pragma unroll
        for (int mt = 0; mt < 4; ++mt)
#pragma unroll
            for (int nt = 0; nt < 8; ++nt)
                acc[mt][nt] = MFMA16(af[mt], bfr[nt], acc[mt][nt]);
    };

    for (int t = 0; t < 14; ++t) {
        int kp = t * 32 + 64;   // prefetch tile t+2
#pragma unroll
        for (int j = 0; j < 2; ++j)
            gl2lds16(Ab + (size_t)(m0 + ar[j]) * 512 + kp + aq[j], a2 + (wv * 2 + j) * 512);
#pragma unroll
        for (int j = 0; j < 4; ++j)
            gl2lds16(Wt + (size_t)(n0 + br[j]) * 512 + kp + bq_[j], b2 + (wv * 4 + j) * 512);
        WAIT_VM(12);           // tile t's 6 loads done; 12 newer in flight
        BAR();
        compute(a0, b0);
        BAR();
        short* ta = a0; a0 = a1; a1 = a2; a2 = ta;
        short* tb = b0; b0 = b1; b1 = b2; b2 = tb;
    }
    WAIT_VM(6); BAR();
    compute(a0, b0);           // tile 14
    WAIT_VM(0); BAR();
    compute(a1, b1);           // tile 15

#pragma unroll
    for (int mt = 0; mt < 4; ++mt) {
#pragma unroll
        for (int nt = 0; nt < 8; ++nt) {
            int n = n0 + wn + nt * 16 + fr;
            float bvv = bias_cat[n];
            int nn = n & 511;
#pragma unroll
            for (int r = 0; r < 4; ++r) {
                int m = m0 + wm + mt * 16 + fq * 4 + r;
                int mrow = permute ? ((m & 31) * 32 + (m >> 5)) : m;
                Ob[(size_t)mrow * 512 + nn] = f2bf(acc[mt][nt][r] + bvv);
            }
        }
    }
}

// ---------------- fused S-GEMM + per-32x32-block softmax diagonal, 128x256 tiles ----------------
__global__ __launch_bounds__(256, 2) void attn_sm(const short* __restrict__ Qp,
                                                  const short* __restrict__ Kp,
                                                  float* __restrict__ Dm) {
    const int tid = threadIdx.x;
    const int wv = tid >> 6, ln = tid & 63;
    // flat id in [0,512); each xcd gets 64 slots = 2 batches x 32 tiles
    const int fid = blockIdx.x + (blockIdx.y << 3) + blockIdx.z * 32;
    const int xcd = fid & 7, slot = fid >> 3;
    const int bb = (slot >= 32) ? 1 : 0;
    const int w = slot - bb * 32;            // [0,32)
    const int b = xcd * 2 + bb;
    const int m0 = (w & 7) * 128, n0 = (w >> 3) * 256;
    const short* Qb = Qp + (size_t)b * (1024 * 512);
    const short* Kb = Kp + (size_t)b * (1024 * 512);

    __shared__ __attribute__((aligned(16))) short As[3][128 * 32];
    __shared__ __attribute__((aligned(16))) short Bs[3][256 * 32];

    floatx4 acc[4][8] = {};
    const int wm = (wv >> 1) * 64, wn = (wv & 1) * 128;
    const int fr = ln & 15, fq = ln >> 4;

    int ar[2], aq[2], br[4], bq_[4];
#pragma unroll
    for (int j = 0; j < 2; ++j) {
        int s = (wv * 2 + j) * 64 + ln;
        ar[j] = s >> 2;
        aq[j] = ((s & 3) ^ ((ar[j] >> 1) & 3)) * 8;
    }
#pragma unroll
    for (int j = 0; j < 4; ++j) {
        int s = (wv * 4 + j) * 64 + ln;
        br[j] = s >> 2;
        bq_[j] = ((s & 3) ^ ((br[j] >> 1) & 3)) * 8;
    }
    int aoff[4], boff[8];
#pragma unroll
    for (int t = 0; t < 4; ++t) {
        int ra = wm + t * 16 + fr;
        aoff[t] = ra * 32 + ((fq ^ ((ra >> 1) & 3)) * 8);
    }
#pragma unroll
    for (int u = 0; u < 8; ++u) {
        int rb = wn + u * 16 + fr;
        boff[u] = rb * 32 + ((fq ^ ((rb >> 1) & 3)) * 8);
    }

    short* a0 = &As[0][0]; short* a1 = &As[1][0]; short* a2 = &As[2][0];
    short* b0 = &Bs[0][0]; short* b1 = &Bs[1][0]; short* b2 = &Bs[2][0];

    // stage tiles 0 and 1 (6 loads each per wave)
#pragma unroll
    for (int j = 0; j < 2; ++j) {
        gl2lds16(Qb + (size_t)(m0 + ar[j]) * 512 + aq[j],      a0 + (wv * 2 + j) * 512);
        gl2lds16(Qb + (size_t)(m0 + ar[j]) * 512 + 32 + aq[j], a1 + (wv * 2 + j) * 512);
    }
#pragma unroll
    for (int j = 0; j < 4; ++j) {
        gl2lds16(Kb + (size_t)(n0 + br[j]) * 512 + bq_[j],      b0 + (wv * 4 + j) * 512);
        gl2lds16(Kb + (size_t)(n0 + br[j]) * 512 + 32 + bq_[j], b1 + (wv * 4 + j) * 512);
    }

    auto compute = [&](const short* Ap, const short* Bp) {
        short8 af[4], bfr[8];
#pragma unroll
        for (int t = 0; t < 4; ++t) af[t] = *(const short8*)(Ap + aoff[t]);
#pragma unroll
        for (int u = 0; u < 8; ++u) bfr[u] = *(const short8*)(Bp + boff[u]);
#pragma unroll
        for (int mt = 0; mt < 4; ++mt)
#pragma unroll
            for (int nt = 0; nt < 8; ++nt)
                acc[mt][nt] = MFMA16(af[mt], bfr[nt], acc[mt][nt]);
    };

    for (int t = 0; t < 14; ++t) {
        int kp = t * 32 + 64;   // prefetch tile t+2
#pragma unroll
        for (int j = 0; j < 2; ++j)
            gl2lds16(Qb + (size_t)(m0 + ar[j]) * 512 + kp + aq[j], a2 + (wv * 2 + j) * 512);
#pragma unroll
        for (int j = 0; j < 4; ++j)
            gl2lds16(Kb + (size_t)(n0 + br[j]) * 512 + kp + bq_[j], b2 + (wv * 4 + j) * 512);
        WAIT_VM(12);           // tile t's 6 loads done; 12 newer in flight
        BAR();
        compute(a0, b0);
        BAR();
        short* ta = a0; a0 = a1; a1 = a2; a2 = ta;
        short* tb = b0; b0 = b1; b1 = b2; b2 = tb;
    }
    WAIT_VM(6); BAR();
    compute(a0, b0);           // tile 14
    WAIT_VM(0); BAR();
    compute(a1, b1);           // tile 15

    // ---- per-slice softmax-diagonal (2x4 = 8 slices per wave) ----
    const float scale = 0.04419417382415922f;  // 512^-0.5
    const int wbase = (m0 + wm) >> 5;
    const int Wbase = (n0 + wn) >> 5;
#pragma unroll
    for (int si = 0; si < 2; ++si) {
#pragma unroll
        for (int sj = 0; sj < 4; ++sj) {
            int wg = wbase + si, Wg = Wbase + sj;
            float tv[16];
            float mx = -3.0e38f;
#pragma unroll
            for (int mi = 0; mi < 2; ++mi)
#pragma unroll
                for (int ni = 0; ni < 2; ++ni)
#pragma unroll
                    for (int r = 0; r < 4; ++r) {
                        float u = acc[2 * si + mi][2 * sj + ni][r] * scale;
                        tv[(mi * 2 + ni) * 4 + r] = u;
                        mx = fmaxf(mx, u);
                    }
#pragma unroll
            for (int off = 32; off > 0; off >>= 1) mx = fmaxf(mx, __shfl_xor(mx, off, 64));
            float se = 0.f;
#pragma unroll
            for (int i = 0; i < 16; ++i) se += __expf(tv[i] - mx);
#pragma unroll
            for (int off = 32; off > 0; off >>= 1) se += __shfl_xor(se, off, 64);
            if (fq == ((wg >> 2) & 3) && fr == (Wg & 15)) {
                int mi = wg >> 4, ni = Wg >> 4;
                float numer = tv[(mi * 2 + ni) * 4 + (wg & 3)];
                Dm[((size_t)b * 32 + wg) * 32 + Wg] = __expf(numer - mx) / se;
            }
        }
    }
}

// ---------------- fused out-GEMM: out[b][n][m] = x + D[b][m]*(V.Wn)[m][n] + bn[n] ----------------
__global__ __launch_bounds__(256) void out_gemm(const short* __restrict__ A,
                                                const short* __restrict__ Wt,
                                                const float* __restrict__ Dm,
                                                const float* __restrict__ bnb,
                                                const float* __restrict__ x,
                                                float* __restrict__ out) {
    const int tid = threadIdx.x;
    const int wv = tid >> 6, ln = tid & 63;
    const int fid = blockIdx.x + (blockIdx.y << 3) + blockIdx.z * 32;
    const int xcd = fid & 7, slot = fid >> 3;
    const int bb = (slot >= 32) ? 1 : 0;
    const int w = slot - bb * 32;
    const int b = xcd * 2 + bb;
    const int m0 = (w & 7) * 128, n0 = (w >> 3) * 128;
    const size_t BS = 1024 * 512;
    const short* Ab = A + (size_t)b * BS;

    __shared__ __attribute__((aligned(16))) short As[3][128 * 32];
    __shared__ __attribute__((aligned(16))) short Bs[3][128 * 32];

    floatx4 acc[4][4] = {};
    const int wm = (wv >> 1) * 64, wn = (wv & 1) * 64;
    const int fr = ln & 15, fq = ln >> 4;

    int sr[2], sq[2];
#pragma unroll
    for (int j = 0; j < 2; ++j) {
        int s = (wv * 2 + j) * 64 + ln;
        sr[j] = s >> 2;
        sq[j] = ((s & 3) ^ ((sr[j] >> 1) & 3)) * 8;
    }
    int aoff[4], boff[4];
#pragma unroll
    for (int t = 0; t < 4; ++t) {
        int ra = wm + t * 16 + fr;
        aoff[t] = ra * 32 + ((fq ^ ((ra >> 1) & 3)) * 8);
        int rb = wn + t * 16 + fr;
        boff[t] = rb * 32 + ((fq ^ ((rb >> 1) & 3)) * 8);
    }

    short* a0 = &As[0][0]; short* a1 = &As[1][0]; short* a2 = &As[2][0];
    short* b0 = &Bs[0][0]; short* b1 = &Bs[1][0]; short* b2 = &Bs[2][0];

#pragma unroll
    for (int j = 0; j < 2; ++j) {
        gl2lds16(Ab + (size_t)(m0 + sr[j]) * 512 + sq[j],      a0 + (wv * 2 + j) * 512);
        gl2lds16(Wt + (size_t)(n0 + sr[j]) * 512 + sq[j],      b0 + (wv * 2 + j) * 512);
        gl2lds16(Ab + (size_t)(m0 + sr[j]) * 512 + 32 + sq[j], a1 + (wv * 2 + j) * 512);
        gl2lds16(Wt + (size_t)(n0 + sr[j]) * 512 + 32 + sq[j], b1 + (wv * 2 + j) * 512);
    }

    auto compute = [&](const short* Ap, const short* Bp) {
        short8 af[4], bfr[4];
#pragma unroll
        for (int t = 0; t < 4; ++t) {
            af[t]  = *(const short8*)(Ap + aoff[t]);
            bfr[t] = *(const short8*)(Bp + boff[t]);
        }
#pragma unroll
        for (int mt = 0; mt < 4; ++mt)
#pragma unroll
            for (int nt = 0; nt < 4; ++nt)
                acc[mt][nt] = MFMA16(af[mt], bfr[nt], acc[mt][nt]);
    };

    for (int t = 0; t < 14; ++t) {
        int kp = t * 32 + 64;
#pragma unroll
        for (int j = 0; j < 2; ++j) {
            gl2lds16(Ab + (size_t)(m0 + sr[j]) * 512 + kp + sq[j], a2 + (wv * 2 + j) * 512);
            gl2lds16(Wt + (size_t)(n0 + sr[j]) * 512 + kp + sq[j], b2 + (wv * 2 + j) * 512);
        }
        WAIT_VM(8);
        BAR();
        compute(a0, b0);
        BAR();
        short* ta = a0; a0 = a1; a1 = a2; a2 = ta;
        short* tb = b0; b0 = b1; b1 = b2; b2 = tb;
    }
    WAIT_VM(4); BAR();
    compute(a0, b0);
    WAIT_VM(0); BAR();
    compute(a1, b1);

#pragma unroll
    for (int mt = 0; mt < 4; ++mt) {
        int mbase = m0 + wm + mt * 16 + fq * 4;
        float4 d4 = *(const float4*)(Dm + (size_t)b * 1024 + mbase);
#pragma unroll
        for (int nt = 0; nt < 4; ++nt) {
            int n = n0 + wn + nt * 16 + fr;
            float bvv = bnb[n];
            size_t base = ((size_t)b * 512 + n) * 1024 + mbase;
            float4 x4 = *(const float4*)(x + base);
            float4 o;
            o.x = x4.x + d4.x * acc[mt][nt][0] + bvv;
            o.y = x4.y + d4.y * acc[mt][nt][1] + bvv;
            o.z = x4.z + d4.z * acc[mt][nt][2] + bvv;
            o.w = x4.w + d4.w * acc[mt][nt][3] + bvv;
            *(float4*)(out + base) = o;
        }
    }
}

extern "C" void kernel_launch(void* const* d_in, const int* in_sizes, int n_in,
                              void* d_out, int out_size, void* d_ws, size_t ws_size,
                              hipStream_t stream) {
    const float* x  = (const float*)d_in[0];
    const float* Wq = (const float*)d_in[1];
    const float* bq = (const float*)d_in[2];
    const float* Wk = (const float*)d_in[3];
    const float* bk = (const float*)d_in[4];
    const float* Wv = (const float*)d_in[5];
    const float* bv = (const float*)d_in[6];
    const float* Wn = (const float*)d_in[7];
    const float* bn = (const float*)d_in[8];
    float* out = (float*)d_out;
    char* ws = (char*)d_ws;

    const size_t WQKV = (size_t)1536 * 512 * 2;       // 1.57 MB
    const size_t WSZ  = (size_t)512 * 512 * 2;        // 0.52 MB
    const size_t BIAS = 1536 * sizeof(float);
    const size_t TSZ  = (size_t)16 * 1024 * 512 * 2;  // 16.78 MB
    short* Wqkv_t   = (short*)(ws);
    short* Wn_t     = (short*)(ws + WQKV);
    float* bias_cat = (float*)(ws + WQKV + WSZ);
    char*  base     = ws + WQKV + WSZ + BIAS;
    short* hnt = (short*)(base);
    short* Qp  = (short*)(base + TSZ);
    short* Kp  = (short*)(base + 2 * TSZ);
    short* Vb  = (short*)(base + 3 * TSZ);
    float* Dm  = (float*)(base + 4 * TSZ);            // 16*1024 fp32

    transpose_w4<<<dim3(16, 16, 4), dim3(32, 8), 0, stream>>>(
        Wq, Wk, Wv, Wn, bq, bk, bv, Wqkv_t, Wn_t, bias_cat);
    groupnorm_k<<<512, 256, 0, stream>>>(x, hnt);
    qkv_gemm<<<dim3(8, 6, 16), 256, 0, stream>>>(hnt, Wqkv_t, bias_cat, Qp, Kp, Vb);
    attn_sm<<<dim3(8, 4, 16), 256, 0, stream>>>(Qp, Kp, Dm);
    out_gemm<<<dim3(8, 4, 16), 256, 0, stream>>>(Vb, Wn_t, Dm, bn, x, out);
}